// Round 7
// baseline (763.306 us; speedup 1.0000x reference)
//
#include <hip/hip_runtime.h>
#include <hip/hip_cooperative_groups.h>
#include <math.h>

namespace cg = cooperative_groups;

#define B_    32
#define NV    32768
#define LA    64
#define DIM   128
#define OUTD  7
#define TOPK  10
#define NMW   (NV / 32)      // 1024 mask words per batch
#define MAXU  (LA * TOPK)    // 640
#define NTASK 2048           // tasks per phase (= B_*LA)
#define HCH   512            // half-chunk verts (8 KB float4 staging)
#define NHC   (NV / HCH)     // 64 half-chunks per batch
#define NSEG  64             // gather segments per batch
#define NTHR  256
#define MAXBLK 2048

// ================= cooperative persistent kernel: all phases, grid-strided =====
__global__ void fused_all(const float* __restrict__ pos, const float* __restrict__ x,
                          const float* __restrict__ lig,
                          const float* __restrict__ W1, const float* __restrict__ b1,
                          const float* __restrict__ gam, const float* __restrict__ bet,
                          const float* __restrict__ rm, const float* __restrict__ rv,
                          const float* __restrict__ W2, const float* __restrict__ b2,
                          float* __restrict__ out,
                          float* __restrict__ T, unsigned int* __restrict__ cnt,
                          unsigned int* __restrict__ maskG, int* __restrict__ cand,
                          int* __restrict__ cntU, double* __restrict__ partial, int cap) {
  cg::grid_group grid = cg::this_grid();
  __shared__ float4 vp[HCH];                 // 8 KB arena (filter stage / list / mlp)
  __shared__ double red[2][DIM];             // 2 KB
  __shared__ unsigned long long kk[4 * TOPK];// 320 B (also float m[] for phase 1)
  __shared__ int wtot[4], wbase[4];
  __shared__ int cntS_sh;
  const int bid = blockIdx.x, tid = threadIdx.x;
  const int nblk = gridDim.x;
  const int w = tid >> 6, lane = tid & 63;

  // ---- phase 0: zero cnt (2048) + maskG (32768 words) --------------------------
  {
    const int total = B_ * LA + B_ * NMW;
    for (int i = bid * NTHR + tid; i < total; i += nblk * NTHR) {
      if (i < B_ * LA) cnt[i] = 0u;
      else maskG[i - B_ * LA] = 0u;
    }
  }

  // ---- phase 1: per-(b,l) sample threshold (block task, 4 waves merge) ---------
  for (int bl = bid; bl < NTASK; bl += nblk) {
    const int b = bl >> 6;
    const float lx = lig[bl * 3 + 0];
    const float ly = lig[bl * 3 + 1];
    const float lz = lig[bl * 3 + 2];
    float* m = (float*)kk;
    float s[TOPK];
#pragma unroll
    for (int i = 0; i < TOPK; ++i) s[i] = INFINITY;
    const float* pb = pos + (size_t)b * NV * 3;
#pragma unroll
    for (int k = 0; k < 8; ++k) {
      int v = w * 512 + lane + 64 * k;
      float dx = pb[v * 3 + 0] - lx;
      float dy = pb[v * 3 + 1] - ly;
      float dz = pb[v * 3 + 2] - lz;
      float d2 = fmaf(dx, dx, fmaf(dy, dy, dz * dz));
      if (d2 < s[TOPK - 1]) {
        s[TOPK - 1] = d2;
#pragma unroll
        for (int i = TOPK - 1; i >= 1; --i)
          if (s[i] < s[i - 1]) { float t = s[i]; s[i] = s[i - 1]; s[i - 1] = t; }
      }
    }
    // wave top-10 (min+consume; dup-consume only enlarges T: safe upper bound)
    for (int r = 0; r < TOPK; ++r) {
      float v = s[0];
#pragma unroll
      for (int o = 1; o < 64; o <<= 1) v = fminf(v, __shfl_xor(v, o, 64));
      if (s[0] == v) {
#pragma unroll
        for (int i = 0; i < TOPK - 1; ++i) s[i] = s[i + 1];
        s[TOPK - 1] = INFINITY;
      }
      if (lane == r) m[w * TOPK + r] = v;
    }
    __syncthreads();
    if (w == 0) {
      float val = (lane < 4 * TOPK) ? m[lane] : INFINITY;
      float T10 = 0.f;
      for (int r = 0; r < TOPK; ++r) {
        float v = val;
#pragma unroll
        for (int o = 1; o < 64; o <<= 1) v = fminf(v, __shfl_xor(v, o, 64));
        T10 = v;
        if (val == v) val = INFINITY;
      }
      if (lane == 0) T[bl] = T10;
    }
    __syncthreads();  // protect m reuse across task iterations
  }
  __threadfence();
  grid.sync();

  // ---- phase 2: filter half-chunks, append candidates with d2 <= T + slack -----
  for (int u = bid; u < B_ * NHC; u += nblk) {
    const int b = u >> 6, c = u & (NHC - 1);
    const int base = c * HCH;
    const float* pb = pos + ((size_t)b * NV + base) * 3;
    __syncthreads();  // protect vp reuse across task iterations
    for (int j = tid; j < HCH * 3; j += NTHR) {
      int v = j / 3, comp = j - 3 * v;
      float val = pb[j];
      if (comp == 0) vp[v].x = val;
      else if (comp == 1) vp[v].y = val;
      else vp[v].z = val;
    }
    __syncthreads();
    for (int v = tid; v < HCH; v += NTHR) {
      float px = vp[v].x, py = vp[v].y, pz = vp[v].z;
      vp[v].w = fmaf(px, px, fmaf(py, py, pz * pz));
    }
    __syncthreads();
    const int lg = tid >> 4, vl = tid & 15;
    float Ax[4], Ay[4], Az[4], TH[4];
#pragma unroll
    for (int j = 0; j < 4; ++j) {
      int l = lg + 16 * j;
      float lx = lig[(b * LA + l) * 3 + 0];
      float ly = lig[(b * LA + l) * 3 + 1];
      float lz = lig[(b * LA + l) * 3 + 2];
      Ax[j] = -2.f * lx; Ay[j] = -2.f * ly; Az[j] = -2.f * lz;
      TH[j] = T[b * LA + l] + 0.01f - (lx * lx + ly * ly + lz * lz);
    }
    for (int k = 0; k < HCH / 16; ++k) {
      int v = vl + 16 * k;
      float4 p = vp[v];
#pragma unroll
      for (int j = 0; j < 4; ++j) {
        float t = fmaf(p.x, Ax[j], fmaf(p.y, Ay[j], fmaf(p.z, Az[j], p.w)));
        if (t <= TH[j]) {
          int l = lg + 16 * j;
          unsigned pidx = atomicAdd(&cnt[b * LA + l], 1u);
          if (pidx < (unsigned)cap) cand[(size_t)(b * LA + l) * cap + pidx] = base + v;
        }
      }
    }
  }
  __threadfence();
  grid.sync();

  // ---- phase 3: exact top-10 over candidates + dedup bits ----------------------
  for (int bl = bid; bl < NTASK; bl += nblk) {
    const int b = bl >> 6;
    const float lx = lig[bl * 3 + 0], ly = lig[bl * 3 + 1], lz = lig[bl * 3 + 2];
    int n = (int)min(cnt[bl], (unsigned)cap);
    unsigned long long s[TOPK];
#pragma unroll
    for (int i = 0; i < TOPK; ++i) s[i] = 0xFFFFFFFFFFFFFFFFull;
    const float* pb = pos + (size_t)b * NV * 3;
    for (int i = w * 64 + lane; i < n; i += 256) {
      int v = cand[(size_t)bl * cap + i];
      float dx = pb[v * 3 + 0] - lx;
      float dy = pb[v * 3 + 1] - ly;
      float dz = pb[v * 3 + 2] - lz;
      float d2 = fmaf(dx, dx, fmaf(dy, dy, dz * dz));
      unsigned long long key =
          ((unsigned long long)__float_as_uint(d2) << 32) | (unsigned int)v;
      if (key < s[TOPK - 1]) {
        s[TOPK - 1] = key;
#pragma unroll
        for (int i2 = TOPK - 1; i2 >= 1; --i2)
          if (s[i2] < s[i2 - 1]) {
            unsigned long long t = s[i2]; s[i2] = s[i2 - 1]; s[i2 - 1] = t;
          }
      }
    }
    for (int r = 0; r < TOPK; ++r) {
      unsigned long long v = s[0];
#pragma unroll
      for (int o = 1; o < 64; o <<= 1) {
        unsigned long long other = __shfl_xor(v, o, 64);
        v = (other < v) ? other : v;
      }
      if (s[0] == v) {
#pragma unroll
        for (int i = 0; i < TOPK - 1; ++i) s[i] = s[i + 1];
        s[TOPK - 1] = 0xFFFFFFFFFFFFFFFFull;
      }
      if (lane == r) kk[w * TOPK + r] = v;
    }
    __syncthreads();
    if (w == 0) {
      unsigned long long key = (lane < 4 * TOPK) ? kk[lane] : 0xFFFFFFFFFFFFFFFFull;
      int prev = 0, myidx = 0;
      for (int r = 0; r < TOPK; ++r) {
        unsigned long long v = key;
#pragma unroll
        for (int o = 1; o < 64; o <<= 1) {
          unsigned long long other = __shfl_xor(v, o, 64);
          v = (other < v) ? other : v;
        }
        if (key == v) key = 0xFFFFFFFFFFFFFFFFull;  // unique keys: exact consume
        int idx = (int)(unsigned int)(v & 0xFFFFFFFFu);
        if ((v >> 32) == 0xFFFFFFFFull) idx = prev;
        prev = idx;
        if (lane == r) myidx = idx;
      }
      if (lane < TOPK)
        atomicOr(&maskG[b * NMW + (myidx >> 5)], 1u << (myidx & 31));
    }
    __syncthreads();  // protect kk reuse
  }
  __threadfence();
  grid.sync();

  // ---- phase 4: mask compaction + segment gather (f64, deterministic) ----------
  for (int u = bid; u < B_ * NSEG; u += nblk) {
    const int b = u >> 6, seg = u & (NSEG - 1);
    int* list = (int*)vp;
    __syncthreads();  // protect vp reuse
    unsigned int wd[4];
    int c = 0;
#pragma unroll
    for (int k = 0; k < 4; ++k) {
      wd[k] = maskG[b * NMW + tid * 4 + k];
      c += __popc(wd[k]);
    }
    int incl = c;
#pragma unroll
    for (int o = 1; o < 64; o <<= 1) {
      int up = __shfl_up(incl, o, 64);
      if (lane >= o) incl += up;
    }
    if (lane == 63) wtot[w] = incl;
    __syncthreads();
    if (tid == 0) {
      int s = 0;
#pragma unroll
      for (int i = 0; i < 4; ++i) { wbase[i] = s; s += wtot[i]; }
      cntS_sh = s;
    }
    __syncthreads();
    int p = wbase[w] + incl - c;
#pragma unroll
    for (int k = 0; k < 4; ++k) {
      unsigned int bits = wd[k];
      while (bits) {
        int bit = __ffs(bits) - 1;
        list[p++] = (tid * 4 + k) * 32 + bit;
        bits &= bits - 1;
      }
    }
    __syncthreads();
    const int n = cntS_sh;
    if (seg == 0 && tid == 0) cntU[b] = n;
    const int r0 = (seg * n) / NSEG, r1 = ((seg + 1) * n) / NSEG;
    const int slot = tid >> 7, col = tid & 127;
    const float* xb = x + (size_t)b * NV * DIM;
    double a0 = 0, a1 = 0, a2 = 0, a3 = 0;
    int i = r0 + slot;
    for (; i + 6 < r1; i += 8) {
      float v0 = xb[(size_t)list[i + 0] * DIM + col];
      float v1 = xb[(size_t)list[i + 2] * DIM + col];
      float v2 = xb[(size_t)list[i + 4] * DIM + col];
      float v3 = xb[(size_t)list[i + 6] * DIM + col];
      a0 += (double)v0; a1 += (double)v1; a2 += (double)v2; a3 += (double)v3;
    }
    for (; i < r1; i += 2) a0 += (double)xb[(size_t)list[i] * DIM + col];
    red[slot][col] = ((a0 + a1) + (a2 + a3));
    __syncthreads();
    if (tid < DIM)
      partial[((size_t)b * NSEG + seg) * DIM + tid] = red[0][tid] + red[1][tid];
  }
  __threadfence();
  grid.sync();

  // ---- phase 5: reduce partials + top_net MLP ----------------------------------
  for (int b = bid; b < B_; b += nblk) {
    float* embS = (float*)vp;            // 512 B
    float* hpart = embS + DIM;           // 1 KB
    float* hS = hpart + 2 * DIM;         // 512 B
    const int t = tid;
    if (t < DIM) {
      double s = 0;
      for (int seg = 0; seg < NSEG; ++seg)
        s += partial[((size_t)b * NSEG + seg) * DIM + t];
      embS[t] = (float)(s / (double)cntU[b]);
    }
    __syncthreads();
    {
      const int d = t & 127, half = t >> 7;
      float hp = 0.f;
      const int dd0 = half * 64;
#pragma unroll 8
      for (int dd = dd0; dd < dd0 + 64; ++dd) hp = fmaf(embS[dd], W1[dd * DIM + d], hp);
      hpart[half * DIM + d] = hp;
    }
    __syncthreads();
    if (t < DIM) {
      float h = hpart[t] + hpart[DIM + t] + b1[t];
      h = (h - rm[t]) / sqrtf(rv[t] + 1e-5f) * gam[t] + bet[t];
      h = h / (1.f + expf(-h));
      hS[t] = h;
    }
    __syncthreads();
    if (t < OUTD * 16) {
      const int o = t >> 4, g = t & 15;
      float p = 0.f;
#pragma unroll
      for (int dd = g * 8; dd < g * 8 + 8; ++dd) p = fmaf(hS[dd], W2[dd * OUTD + o], p);
#pragma unroll
      for (int off = 8; off >= 1; off >>= 1) p += __shfl_down(p, off, 16);
      if (g == 0) out[b * OUTD + o] = p + b2[o];
    }
    __syncthreads();
  }
}

// ================= fallback: proven round-6 5-kernel pipeline ===================
#define CHUNK 1024
#define NCH   (NV / CHUNK)
#define FNSEG 16

__global__ void k1_threshold(const float* __restrict__ pos, const float* __restrict__ lig,
                             float* __restrict__ T, unsigned int* __restrict__ cnt,
                             unsigned int* __restrict__ maskG) {
  __shared__ float m[4 * TOPK];
  const int l = blockIdx.x, b = blockIdx.y;
  const int tid = threadIdx.x, w = tid >> 6, lane = tid & 63;
  const int bl = b * LA + l;
  if (tid == 0) cnt[bl] = 0u;
  if (tid < 16) maskG[b * NMW + l * 16 + tid] = 0u;
  const float lx = lig[bl * 3 + 0];
  const float ly = lig[bl * 3 + 1];
  const float lz = lig[bl * 3 + 2];
  float s[TOPK];
#pragma unroll
  for (int i = 0; i < TOPK; ++i) s[i] = INFINITY;
  const float* pb = pos + (size_t)b * NV * 3;
#pragma unroll
  for (int k = 0; k < 8; ++k) {
    int v = w * 512 + lane + 64 * k;
    float dx = pb[v * 3 + 0] - lx;
    float dy = pb[v * 3 + 1] - ly;
    float dz = pb[v * 3 + 2] - lz;
    float d2 = fmaf(dx, dx, fmaf(dy, dy, dz * dz));
    if (d2 < s[TOPK - 1]) {
      s[TOPK - 1] = d2;
#pragma unroll
      for (int i = TOPK - 1; i >= 1; --i)
        if (s[i] < s[i - 1]) { float t = s[i]; s[i] = s[i - 1]; s[i - 1] = t; }
    }
  }
  for (int r = 0; r < TOPK; ++r) {
    float v = s[0];
#pragma unroll
    for (int o = 1; o < 64; o <<= 1) v = fminf(v, __shfl_xor(v, o, 64));
    if (s[0] == v) {
#pragma unroll
      for (int i = 0; i < TOPK - 1; ++i) s[i] = s[i + 1];
      s[TOPK - 1] = INFINITY;
    }
    if (lane == r) m[w * TOPK + r] = v;
  }
  __syncthreads();
  if (w == 0) {
    float val = (lane < 4 * TOPK) ? m[lane] : INFINITY;
    float T10 = 0.f;
    for (int r = 0; r < TOPK; ++r) {
      float v = val;
#pragma unroll
      for (int o = 1; o < 64; o <<= 1) v = fminf(v, __shfl_xor(v, o, 64));
      T10 = v;
      if (val == v) val = INFINITY;
    }
    if (lane == 0) T[bl] = T10;
  }
}

__global__ void k2_filter(const float* __restrict__ pos, const float* __restrict__ lig,
                          const float* __restrict__ T, unsigned int* __restrict__ cnt,
                          int* __restrict__ cand, int cap) {
  __shared__ float4 vp[CHUNK];
  const int c = blockIdx.x, b = blockIdx.y;
  const int tid = threadIdx.x;
  const int base = c * CHUNK;
  const float* pb = pos + ((size_t)b * NV + base) * 3;
  for (int j = tid; j < CHUNK * 3; j += 256) {
    int v = j / 3, comp = j - 3 * v;
    float val = pb[j];
    if (comp == 0) vp[v].x = val;
    else if (comp == 1) vp[v].y = val;
    else vp[v].z = val;
  }
  __syncthreads();
  for (int v = tid; v < CHUNK; v += 256) {
    float px = vp[v].x, py = vp[v].y, pz = vp[v].z;
    vp[v].w = fmaf(px, px, fmaf(py, py, pz * pz));
  }
  __syncthreads();
  const int lg = tid >> 4, vl = tid & 15;
  float Ax[4], Ay[4], Az[4], TH[4];
#pragma unroll
  for (int j = 0; j < 4; ++j) {
    int l = lg + 16 * j;
    float lx = lig[(b * LA + l) * 3 + 0];
    float ly = lig[(b * LA + l) * 3 + 1];
    float lz = lig[(b * LA + l) * 3 + 2];
    Ax[j] = -2.f * lx; Ay[j] = -2.f * ly; Az[j] = -2.f * lz;
    TH[j] = T[b * LA + l] + 0.01f - (lx * lx + ly * ly + lz * lz);
  }
  for (int k = 0; k < CHUNK / 16; ++k) {
    int v = vl + 16 * k;
    float4 p = vp[v];
#pragma unroll
    for (int j = 0; j < 4; ++j) {
      float t = fmaf(p.x, Ax[j], fmaf(p.y, Ay[j], fmaf(p.z, Az[j], p.w)));
      if (t <= TH[j]) {
        int l = lg + 16 * j;
        unsigned pidx = atomicAdd(&cnt[b * LA + l], 1u);
        if (pidx < (unsigned)cap) cand[(size_t)(b * LA + l) * cap + pidx] = base + v;
      }
    }
  }
}

__global__ void k3_select(const float* __restrict__ pos, const float* __restrict__ lig,
                          const unsigned int* __restrict__ cnt,
                          const int* __restrict__ cand, int cap,
                          unsigned int* __restrict__ maskG) {
  __shared__ unsigned long long kk[4 * TOPK];
  const int bl = blockIdx.x;
  const int b = bl / LA;
  const int tid = threadIdx.x, w = tid >> 6, lane = tid & 63;
  const float lx = lig[bl * 3 + 0], ly = lig[bl * 3 + 1], lz = lig[bl * 3 + 2];
  int n = (int)min(cnt[bl], (unsigned)cap);
  unsigned long long s[TOPK];
#pragma unroll
  for (int i = 0; i < TOPK; ++i) s[i] = 0xFFFFFFFFFFFFFFFFull;
  const float* pb = pos + (size_t)b * NV * 3;
  for (int i = w * 64 + lane; i < n; i += 256) {
    int v = cand[(size_t)bl * cap + i];
    float dx = pb[v * 3 + 0] - lx;
    float dy = pb[v * 3 + 1] - ly;
    float dz = pb[v * 3 + 2] - lz;
    float d2 = fmaf(dx, dx, fmaf(dy, dy, dz * dz));
    unsigned long long key =
        ((unsigned long long)__float_as_uint(d2) << 32) | (unsigned int)v;
    if (key < s[TOPK - 1]) {
      s[TOPK - 1] = key;
#pragma unroll
      for (int i2 = TOPK - 1; i2 >= 1; --i2)
        if (s[i2] < s[i2 - 1]) {
          unsigned long long t = s[i2]; s[i2] = s[i2 - 1]; s[i2 - 1] = t;
        }
    }
  }
  for (int r = 0; r < TOPK; ++r) {
    unsigned long long v = s[0];
#pragma unroll
    for (int o = 1; o < 64; o <<= 1) {
      unsigned long long other = __shfl_xor(v, o, 64);
      v = (other < v) ? other : v;
    }
    if (s[0] == v) {
#pragma unroll
      for (int i = 0; i < TOPK - 1; ++i) s[i] = s[i + 1];
      s[TOPK - 1] = 0xFFFFFFFFFFFFFFFFull;
    }
    if (lane == r) kk[w * TOPK + r] = v;
  }
  __syncthreads();
  if (w == 0) {
    unsigned long long key = (lane < 4 * TOPK) ? kk[lane] : 0xFFFFFFFFFFFFFFFFull;
    int prev = 0, myidx = 0;
    for (int r = 0; r < TOPK; ++r) {
      unsigned long long v = key;
#pragma unroll
      for (int o = 1; o < 64; o <<= 1) {
        unsigned long long other = __shfl_xor(v, o, 64);
        v = (other < v) ? other : v;
      }
      if (key == v) key = 0xFFFFFFFFFFFFFFFFull;
      int idx = (int)(unsigned int)(v & 0xFFFFFFFFu);
      if ((v >> 32) == 0xFFFFFFFFull) idx = prev;
      prev = idx;
      if (lane == r) myidx = idx;
    }
    if (lane < TOPK)
      atomicOr(&maskG[b * NMW + (myidx >> 5)], 1u << (myidx & 31));
  }
}

__global__ void k4a_gather(const float* __restrict__ x, const unsigned int* __restrict__ maskG,
                           int* __restrict__ cntU, double* __restrict__ partial) {
  __shared__ int list[MAXU];
  __shared__ int wtot[4], wbase[4];
  __shared__ int cntS;
  __shared__ double red[2][DIM];
  const int seg = blockIdx.x, b = blockIdx.y, tid = threadIdx.x;
  const int w = tid >> 6, lane = tid & 63;
  unsigned int wd[4];
  int c = 0;
#pragma unroll
  for (int k = 0; k < 4; ++k) {
    wd[k] = maskG[b * NMW + tid * 4 + k];
    c += __popc(wd[k]);
  }
  int incl = c;
#pragma unroll
  for (int o = 1; o < 64; o <<= 1) {
    int up = __shfl_up(incl, o, 64);
    if (lane >= o) incl += up;
  }
  if (lane == 63) wtot[w] = incl;
  __syncthreads();
  if (tid == 0) {
    int s = 0;
#pragma unroll
    for (int i = 0; i < 4; ++i) { wbase[i] = s; s += wtot[i]; }
    cntS = s;
  }
  __syncthreads();
  int p = wbase[w] + incl - c;
#pragma unroll
  for (int k = 0; k < 4; ++k) {
    unsigned int bits = wd[k];
    while (bits) {
      int bit = __ffs(bits) - 1;
      list[p++] = (tid * 4 + k) * 32 + bit;
      bits &= bits - 1;
    }
  }
  __syncthreads();
  const int n = cntS;
  if (seg == 0 && tid == 0) cntU[b] = n;
  const int r0 = (seg * n) / FNSEG, r1 = ((seg + 1) * n) / FNSEG;
  const int slot = tid >> 7, col = tid & 127;
  const float* xb = x + (size_t)b * NV * DIM;
  double a0 = 0, a1 = 0, a2 = 0, a3 = 0;
  int i = r0 + slot;
  for (; i + 6 < r1; i += 8) {
    float v0 = xb[(size_t)list[i + 0] * DIM + col];
    float v1 = xb[(size_t)list[i + 2] * DIM + col];
    float v2 = xb[(size_t)list[i + 4] * DIM + col];
    float v3 = xb[(size_t)list[i + 6] * DIM + col];
    a0 += (double)v0; a1 += (double)v1; a2 += (double)v2; a3 += (double)v3;
  }
  for (; i < r1; i += 2) a0 += (double)xb[(size_t)list[i] * DIM + col];
  red[slot][col] = ((a0 + a1) + (a2 + a3));
  __syncthreads();
  if (tid < DIM)
    partial[((size_t)b * FNSEG + seg) * DIM + tid] = red[0][tid] + red[1][tid];
}

__global__ void k4b_mlp(const double* __restrict__ partial, const int* __restrict__ cntU,
                        const float* __restrict__ W1, const float* __restrict__ b1,
                        const float* __restrict__ gamma, const float* __restrict__ beta,
                        const float* __restrict__ rm, const float* __restrict__ rv,
                        const float* __restrict__ W2, const float* __restrict__ b2,
                        float* __restrict__ out) {
  __shared__ float embS[DIM];
  __shared__ float hpart[2][DIM];
  __shared__ float hS[DIM];
  const int b = blockIdx.x, t = threadIdx.x;
  if (t < DIM) {
    double s = 0;
#pragma unroll
    for (int seg = 0; seg < FNSEG; ++seg)
      s += partial[((size_t)b * FNSEG + seg) * DIM + t];
    embS[t] = (float)(s / (double)cntU[b]);
  }
  __syncthreads();
  {
    const int d = t & 127, half = t >> 7;
    float hp = 0.f;
    const int dd0 = half * 64;
#pragma unroll 8
    for (int dd = dd0; dd < dd0 + 64; ++dd) hp = fmaf(embS[dd], W1[dd * DIM + d], hp);
    hpart[half][d] = hp;
  }
  __syncthreads();
  if (t < DIM) {
    float h = hpart[0][t] + hpart[1][t] + b1[t];
    h = (h - rm[t]) / sqrtf(rv[t] + 1e-5f) * gamma[t] + beta[t];
    h = h / (1.f + expf(-h));
    hS[t] = h;
  }
  __syncthreads();
  if (t < OUTD * 16) {
    const int o = t >> 4, g = t & 15;
    float p = 0.f;
#pragma unroll
    for (int dd = g * 8; dd < g * 8 + 8; ++dd) p = fmaf(hS[dd], W2[dd * OUTD + o], p);
#pragma unroll
    for (int off = 8; off >= 1; off >>= 1) p += __shfl_down(p, off, 16);
    if (g == 0) out[b * OUTD + o] = p + b2[o];
  }
}

extern "C" void kernel_launch(void* const* d_in, const int* in_sizes, int n_in,
                              void* d_out, int out_size, void* d_ws, size_t ws_size,
                              hipStream_t stream) {
  const float* pos  = (const float*)d_in[0];
  const float* x    = (const float*)d_in[1];
  const float* lig  = (const float*)d_in[2];
  const float* W1   = (const float*)d_in[3];
  const float* b1   = (const float*)d_in[4];
  const float* gam  = (const float*)d_in[5];
  const float* bet  = (const float*)d_in[6];
  const float* rm   = (const float*)d_in[7];
  const float* rv   = (const float*)d_in[8];
  const float* W2   = (const float*)d_in[9];
  const float* b2   = (const float*)d_in[10];
  float* out = (float*)d_out;

  // workspace carve-up (partial sized for NSEG=64 coop; fallback FNSEG=16 fits inside)
  char* ws = (char*)d_ws;
  const int NBL = B_ * LA;  // 2048
  float* T            = (float*)(ws);                     // 8 KB
  unsigned int* cnt   = (unsigned int*)(ws + 8192);       // 8 KB
  unsigned int* maskG = (unsigned int*)(ws + 16384);      // 128 KB
  int* cntU           = (int*)(ws + 147456);              // 128 B
  double* partial     = (double*)(ws + 147584);           // 2 MB (32*64*128*8)
  int* cand           = (int*)(ws + 147584 + 2097152);
  size_t fixed = 147584 + 2097152;
  size_t avail = ws_size > fixed ? ws_size - fixed : 0;
  int cap = (int)(avail / ((size_t)NBL * 4));
  if (cap > 1024) cap = 1024;
  if (cap < 16) cap = 16;

  // cooperative path: occupancy-sized persistent kernel (host-only query, capture-safe)
  int occ = 0;
  hipError_t qe = hipOccupancyMaxActiveBlocksPerMultiprocessor(
      &occ, (const void*)fused_all, NTHR, 0);
  int nblk = (qe == hipSuccess && occ > 0) ? occ * 256 : 0;
  if (nblk > MAXBLK) nblk = MAXBLK;

  hipError_t e = hipErrorUnknown;
  if (nblk >= 256) {
    void* args[] = {(void*)&pos, (void*)&x, (void*)&lig, (void*)&W1, (void*)&b1,
                    (void*)&gam, (void*)&bet, (void*)&rm, (void*)&rv, (void*)&W2,
                    (void*)&b2, (void*)&out, (void*)&T, (void*)&cnt, (void*)&maskG,
                    (void*)&cand, (void*)&cntU, (void*)&partial, (void*)&cap};
    e = hipLaunchCooperativeKernel((const void*)fused_all, dim3(nblk),
                                   dim3(NTHR), args, 0, stream);
  }
  if (e != hipSuccess) {
    // fallback: proven round-6 pipeline (identical math, FNSEG=16 partial layout)
    k1_threshold<<<dim3(LA, B_), 256, 0, stream>>>(pos, lig, T, cnt, maskG);
    k2_filter<<<dim3(NCH, B_), 256, 0, stream>>>(pos, lig, T, cnt, cand, cap);
    k3_select<<<NBL, 256, 0, stream>>>(pos, lig, cnt, cand, cap, maskG);
    k4a_gather<<<dim3(FNSEG, B_), 256, 0, stream>>>(x, maskG, cntU, partial);
    k4b_mlp<<<B_, 256, 0, stream>>>(partial, cntU, W1, b1, gam, bet, rm, rv, W2, b2, out);
  }
}

// Round 8
// 226.313 us; speedup vs baseline: 3.3728x; 3.3728x over previous
//
#include <hip/hip_runtime.h>
#include <math.h>

#define B_    32
#define NV    32768
#define LA    64
#define DIM   128
#define OUTD  7
#define TOPK  10
#define CH    512            // verts per chunk
#define NCHK  (NV / CH)      // 64 chunks per batch
#define NSLOT 16             // 10 winners + 6 slack slots per (lig, chunk)
#define NMW   (NV / 32)      // 1024 mask words per batch
#define MAXU  (LA * TOPK)    // 640
#define SLACK 0.05f

typedef unsigned long long u64;

// ---------------- KA: per-chunk exact top-10 per ligand (+slack extras) ---------
// grid (NCHK, B_) = 2048 blocks, 256 threads.
// Thread (lg=tid>>4, vl=tid&15) handles ligs {lg+16j} x verts {vl+16k}.
__global__ void ka_chunktop(const float* __restrict__ pos,
                            const float* __restrict__ lig,
                            int* __restrict__ top16) {
  __shared__ float4 vp[CH];     // 8 KB: x,y,z,pp
  __shared__ int xcnt[16][4];   // extras counters per (lg, j)
  const int c = blockIdx.x, b = blockIdx.y, tid = threadIdx.x;
  const float* pb = pos + ((size_t)b * NV + c * CH) * 3;
  for (int j = tid; j < CH * 3; j += 256) {
    int v = j / 3, comp = j - 3 * v;
    float val = pb[j];
    if (comp == 0) vp[v].x = val;
    else if (comp == 1) vp[v].y = val;
    else vp[v].z = val;
  }
  if (tid < 64) xcnt[tid >> 2][tid & 3] = 0;
  __syncthreads();
  for (int v = tid; v < CH; v += 256) {
    float px = vp[v].x, py = vp[v].y, pz = vp[v].z;
    vp[v].w = fmaf(px, px, fmaf(py, py, pz * pz));
  }
  __syncthreads();
  const int lg = tid >> 4, vl = tid & 15;
  const int base = c * CH;
  for (int j = 0; j < 4; ++j) {
    const int l = lg + 16 * j;
    const float lx = lig[(b * LA + l) * 3 + 0];
    const float ly = lig[(b * LA + l) * 3 + 1];
    const float lz = lig[(b * LA + l) * 3 + 2];
    const float Ax = -2.f * lx, Ay = -2.f * ly, Az = -2.f * lz;
    const float Cl = fmaf(lx, lx, fmaf(ly, ly, lz * lz));
    u64 s[TOPK];
#pragma unroll
    for (int i = 0; i < TOPK; ++i) s[i] = 0xFFFFFFFFFFFFFFFFull;
    for (int k = 0; k < CH / 16; ++k) {
      int v = vl + 16 * k;
      float4 p = vp[v];
      float d2 = fmaf(p.x, Ax, fmaf(p.y, Ay, fmaf(p.z, Az, p.w))) + Cl;
      d2 = fmaxf(d2, 0.f);
      u64 key = ((u64)__float_as_uint(d2) << 32) | (unsigned)(base + v);
      if (key < s[TOPK - 1]) {
        s[TOPK - 1] = key;
#pragma unroll
        for (int i2 = TOPK - 1; i2 >= 1; --i2)
          if (s[i2] < s[i2 - 1]) { u64 t = s[i2]; s[i2] = s[i2 - 1]; s[i2 - 1] = t; }
      }
    }
    // 16-lane merge (keys unique): 10 rounds min+consume
    int* slot = top16 + (((size_t)b * LA + l) * NCHK + c) * NSLOT;
    u64 key10 = 0;
    int w0 = 0;
    for (int r = 0; r < TOPK; ++r) {
      u64 v = s[0];
#pragma unroll
      for (int o = 1; o < 16; o <<= 1) {
        u64 other = __shfl_xor(v, o, 64);
        v = (other < v) ? other : v;
      }
      if (s[0] == v) {
#pragma unroll
        for (int i = 0; i < TOPK - 1; ++i) s[i] = s[i + 1];
        s[TOPK - 1] = 0xFFFFFFFFFFFFFFFFull;
      }
      if (r == 0) w0 = (int)(unsigned)(v & 0xFFFFFFFFu);
      if (r == TOPK - 1) key10 = v;
      if (vl == r) slot[r] = (int)(unsigned)(v & 0xFFFFFFFFu);
    }
    // pad extras slots with winner0 (deterministic), then slack extras overwrite
    if (vl < NSLOT - TOPK) slot[TOPK + vl] = w0;
    const float th = __uint_as_float((unsigned)(key10 >> 32)) + SLACK;
    for (int k = 0; k < CH / 16; ++k) {
      int v = vl + 16 * k;
      float4 p = vp[v];
      float d2 = fmaf(p.x, Ax, fmaf(p.y, Ay, fmaf(p.z, Az, p.w))) + Cl;
      d2 = fmaxf(d2, 0.f);
      u64 key = ((u64)__float_as_uint(d2) << 32) | (unsigned)(base + v);
      if (d2 <= th && key > key10) {
        int e = atomicAdd(&xcnt[lg][j], 1);
        if (e < NSLOT - TOPK) slot[TOPK + e] = base + v;
      }
    }
  }
}

// ---------------- KB: exact select + dedup + gather mean + MLP, one block/batch -
// grid B_, block 1024 (16 waves). Wave w handles ligs 4w..4w+3.
__global__ void kb_all(const float* __restrict__ pos, const float* __restrict__ x,
                       const float* __restrict__ lig, const int* __restrict__ top16,
                       const float* __restrict__ W1, const float* __restrict__ b1,
                       const float* __restrict__ gam, const float* __restrict__ bet,
                       const float* __restrict__ rm, const float* __restrict__ rv,
                       const float* __restrict__ W2, const float* __restrict__ b2,
                       float* __restrict__ out) {
  __shared__ unsigned maskL[NMW];        // 4 KB
  __shared__ int list[MAXU];             // 2.5 KB
  __shared__ double red[8][DIM];         // 8 KB
  __shared__ float embS[DIM];
  __shared__ float hpart[8][DIM];        // 4 KB
  __shared__ float hS[DIM];
  __shared__ int wtot[16], wbase[16], cntS;
  const int b = blockIdx.x, tid = threadIdx.x;
  const int w = tid >> 6, lane = tid & 63;
  for (int i = tid; i < NMW; i += 1024) maskL[i] = 0u;
  __syncthreads();
  // --- exact top-10 per lig over 1024 fixed candidates (diff-of-squares) ---
  const float* pb = pos + (size_t)b * NV * 3;
  for (int j = 0; j < 4; ++j) {
    const int l = w * 4 + j;
    const float lx = lig[(b * LA + l) * 3 + 0];
    const float ly = lig[(b * LA + l) * 3 + 1];
    const float lz = lig[(b * LA + l) * 3 + 2];
    const int* cd = top16 + ((size_t)b * LA + l) * (NCHK * NSLOT);
    u64 s[TOPK];
#pragma unroll
    for (int i = 0; i < TOPK; ++i) s[i] = 0xFFFFFFFFFFFFFFFFull;
#pragma unroll 4
    for (int k = 0; k < (NCHK * NSLOT) / 64; ++k) {  // 16
      int v = cd[lane + 64 * k];
      float dx = pb[v * 3 + 0] - lx;
      float dy = pb[v * 3 + 1] - ly;
      float dz = pb[v * 3 + 2] - lz;
      float d2 = fmaf(dx, dx, fmaf(dy, dy, dz * dz));
      u64 key = ((u64)__float_as_uint(d2) << 32) | (unsigned)v;
      if (key < s[TOPK - 1]) {
        s[TOPK - 1] = key;
#pragma unroll
        for (int i2 = TOPK - 1; i2 >= 1; --i2)
          if (s[i2] < s[i2 - 1]) { u64 t = s[i2]; s[i2] = s[i2 - 1]; s[i2 - 1] = t; }
      }
    }
    // 64-lane merge; duplicates (pads) share keys and are consumed together,
    // so 10 rounds yield the 10 smallest DISTINCT vertices (exact, idx-tiebreak).
    int prev = 0, myidx = 0;
    for (int r = 0; r < TOPK; ++r) {
      u64 v = s[0];
#pragma unroll
      for (int o = 1; o < 64; o <<= 1) {
        u64 other = __shfl_xor(v, o, 64);
        v = (other < v) ? other : v;
      }
      if (s[0] == v) {
#pragma unroll
        for (int i = 0; i < TOPK - 1; ++i) s[i] = s[i + 1];
        s[TOPK - 1] = 0xFFFFFFFFFFFFFFFFull;
      }
      int idx = (int)(unsigned)(v & 0xFFFFFFFFu);
      if ((v >> 32) == 0xFFFFFFFFull) idx = prev;  // pad guard (impossible here)
      prev = idx;
      if (lane == r) myidx = idx;
    }
    if (lane < TOPK)
      atomicOr(&maskL[myidx >> 5], 1u << (myidx & 31));
  }
  __syncthreads();
  // --- dedup: block-wide exclusive scan over popcounts (deterministic) ---
  unsigned bits = maskL[tid];
  int c = __popc(bits);
  int incl = c;
#pragma unroll
  for (int o = 1; o < 64; o <<= 1) {
    int up = __shfl_up(incl, o, 64);
    if (lane >= o) incl += up;
  }
  if (lane == 63) wtot[w] = incl;
  __syncthreads();
  if (tid == 0) {
    int ssum = 0;
#pragma unroll
    for (int i = 0; i < 16; ++i) { wbase[i] = ssum; ssum += wtot[i]; }
    cntS = ssum;
  }
  __syncthreads();
  int p = wbase[w] + incl - c;
  while (bits) {
    int bit = __ffs(bits) - 1;
    list[p++] = tid * 32 + bit;
    bits &= bits - 1;
  }
  __syncthreads();
  const int n = cntS;
  // --- gather-sum (f64, fixed order): 8 row-slots x 128 cols ---
  const int slot = tid >> 7, col = tid & 127;
  const float* xb = x + (size_t)b * NV * DIM;
  double a0 = 0, a1 = 0, a2 = 0, a3 = 0;
  int i = slot;
  for (; i + 24 < n; i += 32) {
    float v0 = xb[(size_t)list[i +  0] * DIM + col];
    float v1 = xb[(size_t)list[i +  8] * DIM + col];
    float v2 = xb[(size_t)list[i + 16] * DIM + col];
    float v3 = xb[(size_t)list[i + 24] * DIM + col];
    a0 += (double)v0; a1 += (double)v1; a2 += (double)v2; a3 += (double)v3;
  }
  for (; i < n; i += 8) a0 += (double)xb[(size_t)list[i] * DIM + col];
  red[slot][col] = ((a0 + a1) + (a2 + a3));
  __syncthreads();
  if (tid < DIM) {
    double ssum = 0;
#pragma unroll
    for (int r = 0; r < 8; ++r) ssum += red[r][tid];
    embS[tid] = (float)(ssum / (double)n);
  }
  __syncthreads();
  // --- Linear1 (8-way split) + BN(eval) + SiLU ---
  {
    const int d = tid & 127, oct = tid >> 7;
    float hp = 0.f;
    const int dd0 = oct * 16;
#pragma unroll
    for (int dd = dd0; dd < dd0 + 16; ++dd) hp = fmaf(embS[dd], W1[dd * DIM + d], hp);
    hpart[oct][d] = hp;
  }
  __syncthreads();
  if (tid < DIM) {
    float h = b1[tid];
#pragma unroll
    for (int r = 0; r < 8; ++r) h += hpart[r][tid];
    h = (h - rm[tid]) / sqrtf(rv[tid] + 1e-5f) * gam[tid] + bet[tid];
    h = h / (1.f + expf(-h));
    hS[tid] = h;
  }
  __syncthreads();
  if (tid < OUTD * 16) {
    const int o = tid >> 4, g = tid & 15;
    float pacc = 0.f;
#pragma unroll
    for (int dd = g * 8; dd < g * 8 + 8; ++dd) pacc = fmaf(hS[dd], W2[dd * OUTD + o], pacc);
#pragma unroll
    for (int off = 8; off >= 1; off >>= 1) pacc += __shfl_down(pacc, off, 16);
    if (g == 0) out[b * OUTD + o] = pacc + b2[o];
  }
}

extern "C" void kernel_launch(void* const* d_in, const int* in_sizes, int n_in,
                              void* d_out, int out_size, void* d_ws, size_t ws_size,
                              hipStream_t stream) {
  const float* pos  = (const float*)d_in[0];
  const float* x    = (const float*)d_in[1];
  const float* lig  = (const float*)d_in[2];
  const float* W1   = (const float*)d_in[3];
  const float* b1   = (const float*)d_in[4];
  const float* gam  = (const float*)d_in[5];
  const float* bet  = (const float*)d_in[6];
  const float* rm   = (const float*)d_in[7];
  const float* rv   = (const float*)d_in[8];
  const float* W2   = (const float*)d_in[9];
  const float* b2   = (const float*)d_in[10];
  float* out = (float*)d_out;

  // workspace: top16 only — [B][LA][NCHK][NSLOT] ints = 8 MB
  int* top16 = (int*)d_ws;

  ka_chunktop<<<dim3(NCHK, B_), 256, 0, stream>>>(pos, lig, top16);
  kb_all<<<B_, 1024, 0, stream>>>(pos, x, lig, top16, W1, b1, gam, bet, rm, rv,
                                  W2, b2, out);
}